// Round 3
// baseline (15674.301 us; speedup 1.0000x reference)
//
#include <hip/hip_runtime.h>
#include <math.h>

// Problem constants
#define B_ 4
#define S_ 2048
#define E_ 512
#define H_ 8
#define D_ 64
#define M1_ (B_ * S_)        // 8192 rows of x
#define NQKV_ (3 * E_)       // 1536
#define BHD_ ((size_t)B_ * H_ * S_ * D_)  // elements per q/k/v buffer = 4,194,304
#define NEG_ (-1.0e30f)      // finite "masked" sentinel (fast-math safe)

// ---------------------------------------------------------------------------
// GEMM1: Y[m,n] = sum_k x[m,k] * W_in[n,k]; scatter to q/k/v fp32 [B*H][S][D]
// Tile 64x64, BK=16, 256 threads, 4x4 accum per thread. All fp32.
// ---------------------------------------------------------------------------
__global__ __launch_bounds__(256) void gemm_qkv(
    const float* __restrict__ X,     // [8192][512]
    const float* __restrict__ Win,   // [1536][512]
    float* __restrict__ qb, float* __restrict__ kb, float* __restrict__ vb) {
  __shared__ float As[16][65];
  __shared__ float Bs[16][65];
  const int tid = threadIdx.x;
  const int tx = tid & 15, ty = tid >> 4;
  const int m0 = blockIdx.x * 64;
  const int n0 = blockIdx.y * 64;
  float acc[4][4] = {};
  for (int k0 = 0; k0 < E_; k0 += 16) {
    for (int l = 0; l < 4; ++l) {
      int e = tid + 256 * l;
      int ml = e >> 4, kl = e & 15;
      As[kl][ml] = X[(size_t)(m0 + ml) * E_ + k0 + kl];
      Bs[kl][ml] = Win[(size_t)(n0 + ml) * E_ + k0 + kl];
    }
    __syncthreads();
    for (int k = 0; k < 16; ++k) {
      float a[4], bv[4];
      for (int i = 0; i < 4; ++i) a[i] = As[k][ty * 4 + i];
      for (int j = 0; j < 4; ++j) bv[j] = Bs[k][tx * 4 + j];
      for (int i = 0; i < 4; ++i)
        for (int j = 0; j < 4; ++j) acc[i][j] += a[i] * bv[j];
    }
    __syncthreads();
  }
  // n0 is a multiple of 64 -> this tile is exactly one (which, head) pair
  const int t3 = n0 >> 9;            // 0=q 1=k 2=v
  const int h = (n0 >> 6) & 7;
  float* dst = (t3 == 0) ? qb : ((t3 == 1) ? kb : vb);
  for (int i = 0; i < 4; ++i) {
    int m = m0 + ty * 4 + i;
    int b = m >> 11, s = m & (S_ - 1);
    float* row = dst + (((size_t)(b * H_ + h)) * S_ + s) * D_;
    for (int j = 0; j < 4; ++j) {
      row[tx * 4 + j] = acc[i][j];
    }
  }
}

// ---------------------------------------------------------------------------
// RoPE in-place on q,k: pairs (2i, 2i+1), i in [0,16), angle = s * theta^(-2i/32)
// ---------------------------------------------------------------------------
__global__ __launch_bounds__(256) void rope_kernel(float* __restrict__ qb,
                                                   float* __restrict__ kb) {
  int idx = blockIdx.x * 256 + threadIdx.x;   // B*H*S*16 = 1,048,576 threads
  int i = idx & 15;
  int s = (idx >> 4) & (S_ - 1);
  int bh = idx >> 15;
  float freq = (float)pow(10000.0, -(double)(2 * i) / 32.0);
  float ang = (float)s * freq;
  float sn, cs;
  sincosf(ang, &sn, &cs);
  size_t base = (((size_t)bh * S_) + s) * D_ + 2 * i;
  float q1 = qb[base], q2 = qb[base + 1];
  qb[base]     = q1 * cs - q2 * sn;
  qb[base + 1] = q1 * sn + q2 * cs;
  float k1 = kb[base], k2 = kb[base + 1];
  kb[base]     = k1 * cs - k2 * sn;
  kb[base + 1] = k1 * sn + k2 * cs;
}

// ---------------------------------------------------------------------------
// Flash attention, fp32. BR=32 query rows per block, BC=64 key cols per tile.
// 256 threads: thread t -> row r = t>>3, col-group g = t&7 (8 acc cols each).
// mask rule: allowed(s,t) = (t<=s) && ((mask[s]&&mask[t]) || t==s)
// All masked-score handling uses finite sentinels (no +-inf -> fast-math safe).
// ---------------------------------------------------------------------------
__global__ __launch_bounds__(256) void flash_kernel(
    const float* __restrict__ qb, const float* __restrict__ kb,
    const float* __restrict__ vb, const int* __restrict__ maskp,
    float* __restrict__ ob) {
  __shared__ float Qs[32][65];
  __shared__ float Ks[64][65];
  __shared__ float Vs[64][65];
  __shared__ float Ps[32][65];
  __shared__ int qmask[32];
  __shared__ int kmask[64];
  const int tid = threadIdx.x;
  const int bh = blockIdx.y;
  const int b = bh >> 3;
  const int h = bh & 7;
  const int r0 = blockIdx.x * 32;
  const float* qbase = qb + (size_t)bh * S_ * D_;
  const float* kbase = kb + (size_t)bh * S_ * D_;
  const float* vbase = vb + (size_t)bh * S_ * D_;
  // load Q tile (32x64)
  for (int l = 0; l < 8; ++l) {
    int e = tid + 256 * l;
    int r = e >> 6, d = e & 63;
    Qs[r][d] = qbase[(size_t)(r0 + r) * D_ + d];
  }
  if (tid < 32) qmask[tid] = maskp[b * S_ + r0 + tid];
  const int r = tid >> 3;
  const int g = tid & 7;
  float m_r = NEG_, l_r = 0.f;
  float acc[8];
  for (int j = 0; j < 8; ++j) acc[j] = 0.f;
  const int ntiles = (r0 + 32 + 63) >> 6;
  for (int kt = 0; kt < ntiles; ++kt) {
    const int t0 = kt * 64;
    __syncthreads();  // Qs ready (first iter); Ks/Vs/Ps no longer in use (later iters)
    for (int l = 0; l < 16; ++l) {
      int e = tid + 256 * l;
      int c = e >> 6, d = e & 63;
      Ks[c][d] = kbase[(size_t)(t0 + c) * D_ + d];
      Vs[c][d] = vbase[(size_t)(t0 + c) * D_ + d];
    }
    if (tid < 64) kmask[tid] = maskp[b * S_ + t0 + tid];
    __syncthreads();
    // scores for (row r, cols g+8j)
    float sc[8];
    for (int j = 0; j < 8; ++j) {
      int c = g + 8 * j;
      float dot = 0.f;
      for (int d = 0; d < 64; ++d) dot += Qs[r][d] * Ks[c][d];
      int tg = t0 + c, sg = r0 + r;
      bool ok = (tg <= sg) && (((qmask[r] != 0) && (kmask[c] != 0)) || (tg == sg));
      sc[j] = ok ? dot * 0.125f : NEG_;
    }
    // row max across my 8 + the 8 lanes sharing this row (contiguous lanes)
    float lm = sc[0];
    for (int j = 1; j < 8; ++j) lm = fmaxf(lm, sc[j]);
    for (int o = 1; o < 8; o <<= 1) lm = fmaxf(lm, __shfl_xor(lm, o, 64));
    float m_new = fmaxf(m_r, lm);
    // alpha: both-sentinel -> exp(0)=1 on zero state (harmless);
    // sentinel->finite -> exp(-1e30)=0; normal case exp(m_r-m_new)<=1.
    float alpha = __expf(m_r - m_new);
    float psum = 0.f;
    for (int j = 0; j < 8; ++j) {
      float p = (sc[j] > -1.0e29f) ? __expf(sc[j] - m_new) : 0.f;
      psum += p;
      Ps[r][g + 8 * j] = p;
    }
    for (int o = 1; o < 8; o <<= 1) psum += __shfl_xor(psum, o, 64);
    l_r = alpha * l_r + psum;
    m_r = m_new;
    // PV accumulate (Ps row r written+read only by this row's 8 lanes, same wave)
    for (int j = 0; j < 8; ++j) acc[j] *= alpha;
    for (int c = 0; c < 64; ++c) {
      float p = Ps[r][c];
      for (int j = 0; j < 8; ++j) acc[j] += p * Vs[c][g + 8 * j];
    }
  }
  // epilogue: attn[b][h][s][d] -> ob[b][s][h*64+d]
  // l_r >= exp(0)=1 contribution from the always-alive diagonal -> no div by 0
  float inv_l = 1.f / l_r;
  for (int j = 0; j < 8; ++j) {
    int d = g + 8 * j;
    ob[((size_t)(b * S_ + r0 + r)) * E_ + h * D_ + d] = acc[j] * inv_l;
  }
}

// ---------------------------------------------------------------------------
// GEMM2: out[m,n] = sum_k ob[m,k] * W_out[n,k]; out fp32
// ---------------------------------------------------------------------------
__global__ __launch_bounds__(256) void gemm_out(
    const float* __restrict__ A,      // [8192][512]
    const float* __restrict__ Wout,   // [512][512]
    float* __restrict__ out) {
  __shared__ float As[16][65];
  __shared__ float Bs[16][65];
  const int tid = threadIdx.x;
  const int tx = tid & 15, ty = tid >> 4;
  const int m0 = blockIdx.x * 64;
  const int n0 = blockIdx.y * 64;
  float acc[4][4] = {};
  for (int k0 = 0; k0 < E_; k0 += 16) {
    for (int l = 0; l < 4; ++l) {
      int e = tid + 256 * l;
      int ml = e >> 4, kl = e & 15;
      As[kl][ml] = A[(size_t)(m0 + ml) * E_ + k0 + kl];
      Bs[kl][ml] = Wout[(size_t)(n0 + ml) * E_ + k0 + kl];
    }
    __syncthreads();
    for (int k = 0; k < 16; ++k) {
      float a[4], bv[4];
      for (int i = 0; i < 4; ++i) a[i] = As[k][ty * 4 + i];
      for (int j = 0; j < 4; ++j) bv[j] = Bs[k][tx * 4 + j];
      for (int i = 0; i < 4; ++i)
        for (int j = 0; j < 4; ++j) acc[i][j] += a[i] * bv[j];
    }
    __syncthreads();
  }
  for (int i = 0; i < 4; ++i) {
    int m = m0 + ty * 4 + i;
    for (int j = 0; j < 4; ++j) {
      int n = n0 + tx * 4 + j;
      out[(size_t)m * E_ + n] = acc[i][j];
    }
  }
}

extern "C" void kernel_launch(void* const* d_in, const int* in_sizes, int n_in,
                              void* d_out, int out_size, void* d_ws, size_t ws_size,
                              hipStream_t stream) {
  const float* x    = (const float*)d_in[0];
  const int*   mask = (const int*)d_in[1];
  const float* Win  = (const float*)d_in[2];
  const float* Wout = (const float*)d_in[3];
  float* out = (float*)d_out;

  float* qb = (float*)d_ws;
  float* kb = qb + BHD_;
  float* vb = kb + BHD_;
  float* ob = vb + BHD_;   // [B][S][E] fp32; total ws use = 64 MiB

  // 1) qkv projection + scatter
  gemm_qkv<<<dim3(M1_ / 64, NQKV_ / 64), 256, 0, stream>>>(x, Win, qb, kb, vb);
  // 2) RoPE on q and k
  rope_kernel<<<(B_ * H_ * S_ * 16) / 256, 256, 0, stream>>>(qb, kb);
  // 3) masked causal flash attention
  flash_kernel<<<dim3(S_ / 32, B_ * H_), 256, 0, stream>>>(qb, kb, vb, mask, ob);
  // 4) output projection
  gemm_out<<<dim3(M1_ / 64, E_ / 64), 256, 0, stream>>>(ob, Wout, out);
}

// Round 4
// 673.331 us; speedup vs baseline: 23.2788x; 23.2788x over previous
//
#include <hip/hip_runtime.h>
#include <math.h>

// Problem constants
#define B_ 4
#define S_ 2048
#define E_ 512
#define H_ 8
#define D_ 64
#define M1_ (B_ * S_)
#define NQKV_ (3 * E_)
#define BHD_ ((size_t)B_ * H_ * S_ * D_)
#define NEG_ (-1.0e30f)

typedef short bf16x8 __attribute__((ext_vector_type(8)));
typedef float f32x4 __attribute__((ext_vector_type(4)));

__device__ inline short f2bf(float f) {  // fp32 -> bf16 bits, RNE
  union { float f; unsigned u; } v; v.f = f;
  unsigned r = v.u + 0x7FFF + ((v.u >> 16) & 1);
  return (short)(r >> 16);
}

// ---------------------------------------------------------------------------
// GEMM1 (unchanged, fp32): Y = x @ W_in^T, scatter q/k/v [B*H][S][D]
// ---------------------------------------------------------------------------
__global__ __launch_bounds__(256) void gemm_qkv(
    const float* __restrict__ X, const float* __restrict__ Win,
    float* __restrict__ qb, float* __restrict__ kb, float* __restrict__ vb) {
  __shared__ float As[16][65];
  __shared__ float Bs[16][65];
  const int tid = threadIdx.x;
  const int tx = tid & 15, ty = tid >> 4;
  const int m0 = blockIdx.x * 64;
  const int n0 = blockIdx.y * 64;
  float acc[4][4] = {};
  for (int k0 = 0; k0 < E_; k0 += 16) {
    for (int l = 0; l < 4; ++l) {
      int e = tid + 256 * l;
      int ml = e >> 4, kl = e & 15;
      As[kl][ml] = X[(size_t)(m0 + ml) * E_ + k0 + kl];
      Bs[kl][ml] = Win[(size_t)(n0 + ml) * E_ + k0 + kl];
    }
    __syncthreads();
    for (int k = 0; k < 16; ++k) {
      float a[4], bv[4];
      for (int i = 0; i < 4; ++i) a[i] = As[k][ty * 4 + i];
      for (int j = 0; j < 4; ++j) bv[j] = Bs[k][tx * 4 + j];
      for (int i = 0; i < 4; ++i)
        for (int j = 0; j < 4; ++j) acc[i][j] += a[i] * bv[j];
    }
    __syncthreads();
  }
  const int t3 = n0 >> 9;
  const int h = (n0 >> 6) & 7;
  float* dst = (t3 == 0) ? qb : ((t3 == 1) ? kb : vb);
  for (int i = 0; i < 4; ++i) {
    int m = m0 + ty * 4 + i;
    int b = m >> 11, s = m & (S_ - 1);
    float* row = dst + (((size_t)(b * H_ + h)) * S_ + s) * D_;
    for (int j = 0; j < 4; ++j) row[tx * 4 + j] = acc[i][j];
  }
}

// ---------------------------------------------------------------------------
// RoPE (unchanged)
// ---------------------------------------------------------------------------
__global__ __launch_bounds__(256) void rope_kernel(float* __restrict__ qb,
                                                   float* __restrict__ kb) {
  int idx = blockIdx.x * 256 + threadIdx.x;
  int i = idx & 15;
  int s = (idx >> 4) & (S_ - 1);
  int bh = idx >> 15;
  float freq = (float)pow(10000.0, -(double)(2 * i) / 32.0);
  float ang = (float)s * freq;
  float sn, cs;
  sincosf(ang, &sn, &cs);
  size_t base = (((size_t)bh * S_) + s) * D_ + 2 * i;
  float q1 = qb[base], q2 = qb[base + 1];
  qb[base]     = q1 * cs - q2 * sn;
  qb[base + 1] = q1 * sn + q2 * cs;
  float k1 = kb[base], k2 = kb[base + 1];
  kb[base]     = k1 * cs - k2 * sn;
  kb[base + 1] = k1 * sn + k2 * cs;
}

// ---------------------------------------------------------------------------
// Flash attention via MFMA 16x16x32 bf16.
// Block = 4 waves; BR=64 q-rows/block (16 per wave); BC=32 k-cols/tile.
// Layouts (HW-verified per guide):
//   A-frag: lane holds A[m=lane&15][k=quad*8+j], j=0..7 (+32*s slice)
//   B-frag: lane holds B[k=quad*8+j][n=lane&15]
//   C/D:    lane holds D[row=quad*4+reg][col=lane&15]
// P goes C-layout -> LDS (bf16) -> A-layout (guide's verified transform).
// V staged in LDS pre-transposed to B-frag order: VB[no][n][k] = V[t0+k][16no+n].
// ---------------------------------------------------------------------------
__global__ __launch_bounds__(256) void flash_mfma(
    const float* __restrict__ qb, const float* __restrict__ kb,
    const float* __restrict__ vb, const int* __restrict__ maskp,
    float* __restrict__ ob) {
  __shared__ short Ks[32][72];       // K tile row-major, pad 72 (16B-aligned rows)
  __shared__ short VB[4][16][40];    // V tile in B-frag order, pad 40
  __shared__ short Pl[4][16][40];    // per-wave P tile (m x t), pad 40
  __shared__ int qmask[64];
  __shared__ int kmask[32];
  const int tid = threadIdx.x;
  const int w = tid >> 6, lane = tid & 63;
  const int l15 = lane & 15, quad = lane >> 4;
  const int bh = blockIdx.y, b = bh >> 3, h = bh & 7;
  const int r0 = blockIdx.x * 64;
  const float* qbase = qb + (size_t)bh * S_ * D_;
  const float* kbase = kb + (size_t)bh * S_ * D_;
  const float* vbase = vb + (size_t)bh * S_ * D_;

  // Q A-frags, once per block: rows r0+16w..+15 for wave w
  bf16x8 aq[2];
  {
    const float* qrow = qbase + (size_t)(r0 + 16 * w + l15) * D_;
    for (int s = 0; s < 2; ++s)
      for (int j = 0; j < 8; ++j)
        aq[s][j] = f2bf(qrow[32 * s + quad * 8 + j]);
  }
  if (tid < 64) qmask[tid] = maskp[b * S_ + r0 + tid];

  f32x4 o[4];                        // O accum: col=l15+16*no, row=quad*4+i
  for (int no = 0; no < 4; ++no) o[no] = (f32x4){0.f, 0.f, 0.f, 0.f};
  float m_run[4], l_run[4];
  for (int i = 0; i < 4; ++i) { m_run[i] = NEG_; l_run[i] = 0.f; }

  const int ntiles = (r0 >> 5) + 2;  // covers t0 <= r0+32 (causal)
  for (int kt = 0; kt < ntiles; ++kt) {
    const int t0 = kt * 32;
    __syncthreads();   // previous tile fully consumed
    {
      const int c = tid >> 3, c0 = (tid & 7) * 8;
      const float* krow = kbase + (size_t)(t0 + c) * D_ + c0;
      const float* vrow = vbase + (size_t)(t0 + c) * D_ + c0;
      for (int j = 0; j < 8; ++j) {
        Ks[c][c0 + j] = f2bf(krow[j]);
        int col = c0 + j;
        VB[col >> 4][col & 15][c] = f2bf(vrow[j]);
      }
      if (tid < 32) kmask[tid] = maskp[b * S_ + t0 + tid];
    }
    __syncthreads();
    // S = Q K^T  (16x32 per wave: 2 col-blocks x 2 k-slices)
    f32x4 sfr[2] = {(f32x4){0.f,0.f,0.f,0.f}, (f32x4){0.f,0.f,0.f,0.f}};
    for (int nb = 0; nb < 2; ++nb)
      for (int s = 0; s < 2; ++s) {
        bf16x8 bk = *(const bf16x8*)&Ks[l15 + 16 * nb][32 * s + quad * 8];
        sfr[nb] = __builtin_amdgcn_mfma_f32_16x16x32_bf16(aq[s], bk, sfr[nb], 0, 0, 0);
      }
    // masked online softmax; row i state replicated across the 16 lanes of a quad
    float p[2][4], alpha[4];
    for (int i = 0; i < 4; ++i) {
      const int sg = r0 + 16 * w + quad * 4 + i;
      const int qm = qmask[16 * w + quad * 4 + i];
      float msc[2];
      for (int nb = 0; nb < 2; ++nb) {
        const int tg = t0 + l15 + 16 * nb;
        bool ok = (tg <= sg) && (((qm != 0) && (kmask[l15 + 16 * nb] != 0)) || (tg == sg));
        msc[nb] = ok ? sfr[nb][i] * 0.125f : NEG_;
      }
      float lm = fmaxf(msc[0], msc[1]);
      for (int o2 = 1; o2 < 16; o2 <<= 1) lm = fmaxf(lm, __shfl_xor(lm, o2, 64));
      float m_new = fmaxf(m_run[i], lm);
      alpha[i] = __expf(m_run[i] - m_new);
      float ps = 0.f;
      for (int nb = 0; nb < 2; ++nb) {
        float pe = (msc[nb] > -1.0e29f) ? __expf(msc[nb] - m_new) : 0.f;
        p[nb][i] = pe; ps += pe;
      }
      for (int o2 = 1; o2 < 16; o2 <<= 1) ps += __shfl_xor(ps, o2, 64);
      l_run[i] = alpha[i] * l_run[i] + ps;
      m_run[i] = m_new;
    }
    // P: C-layout regs -> LDS (own wave's region; same-wave DS ops are in-order)
    for (int nb = 0; nb < 2; ++nb)
      for (int i = 0; i < 4; ++i)
        Pl[w][quad * 4 + i][l15 + 16 * nb] = f2bf(p[nb][i]);
    for (int no = 0; no < 4; ++no)
      for (int i = 0; i < 4; ++i) o[no][i] *= alpha[i];
    asm volatile("s_waitcnt lgkmcnt(0)" ::: "memory");
    bf16x8 ap = *(const bf16x8*)&Pl[w][l15][quad * 8];
    for (int no = 0; no < 4; ++no) {
      bf16x8 bv = *(const bf16x8*)&VB[no][l15][quad * 8];
      o[no] = __builtin_amdgcn_mfma_f32_16x16x32_bf16(ap, bv, o[no], 0, 0, 0);
    }
  }
  // epilogue: attn[b][h][s][d] -> ob[b][s][h*64+d]
  for (int i = 0; i < 4; ++i) {
    const int s = r0 + 16 * w + quad * 4 + i;
    const float inv = 1.f / l_run[i];
    float* orow = ob + ((size_t)(b * S_ + s)) * E_ + h * D_;
    for (int no = 0; no < 4; ++no)
      orow[l15 + 16 * no] = o[no][i] * inv;
  }
}

// ---------------------------------------------------------------------------
// GEMM2 (unchanged, fp32): out = ob @ W_out^T
// ---------------------------------------------------------------------------
__global__ __launch_bounds__(256) void gemm_out(
    const float* __restrict__ A, const float* __restrict__ Wout,
    float* __restrict__ out) {
  __shared__ float As[16][65];
  __shared__ float Bs[16][65];
  const int tid = threadIdx.x;
  const int tx = tid & 15, ty = tid >> 4;
  const int m0 = blockIdx.x * 64;
  const int n0 = blockIdx.y * 64;
  float acc[4][4] = {};
  for (int k0 = 0; k0 < E_; k0 += 16) {
    for (int l = 0; l < 4; ++l) {
      int e = tid + 256 * l;
      int ml = e >> 4, kl = e & 15;
      As[kl][ml] = A[(size_t)(m0 + ml) * E_ + k0 + kl];
      Bs[kl][ml] = Wout[(size_t)(n0 + ml) * E_ + k0 + kl];
    }
    __syncthreads();
    for (int k = 0; k < 16; ++k) {
      float a[4], bv[4];
      for (int i = 0; i < 4; ++i) a[i] = As[k][ty * 4 + i];
      for (int j = 0; j < 4; ++j) bv[j] = Bs[k][tx * 4 + j];
      for (int i = 0; i < 4; ++i)
        for (int j = 0; j < 4; ++j) acc[i][j] += a[i] * bv[j];
    }
    __syncthreads();
  }
  for (int i = 0; i < 4; ++i) {
    int m = m0 + ty * 4 + i;
    for (int j = 0; j < 4; ++j) {
      int n = n0 + tx * 4 + j;
      out[(size_t)m * E_ + n] = acc[i][j];
    }
  }
}

extern "C" void kernel_launch(void* const* d_in, const int* in_sizes, int n_in,
                              void* d_out, int out_size, void* d_ws, size_t ws_size,
                              hipStream_t stream) {
  const float* x    = (const float*)d_in[0];
  const int*   mask = (const int*)d_in[1];
  const float* Win  = (const float*)d_in[2];
  const float* Wout = (const float*)d_in[3];
  float* out = (float*)d_out;

  float* qb = (float*)d_ws;
  float* kb = qb + BHD_;
  float* vb = kb + BHD_;
  float* ob = vb + BHD_;

  gemm_qkv<<<dim3(M1_ / 64, NQKV_ / 64), 256, 0, stream>>>(x, Win, qb, kb, vb);
  rope_kernel<<<(B_ * H_ * S_ * 16) / 256, 256, 0, stream>>>(qb, kb);
  flash_mfma<<<dim3(S_ / 64, B_ * H_), 256, 0, stream>>>(qb, kb, vb, mask, ob);
  gemm_out<<<dim3(M1_ / 64, E_ / 64), 256, 0, stream>>>(ob, Wout, out);
}

// Round 5
// 380.709 us; speedup vs baseline: 41.1713x; 1.7686x over previous
//
#include <hip/hip_runtime.h>
#include <math.h>

// Problem constants
#define B_ 4
#define S_ 2048
#define E_ 512
#define H_ 8
#define D_ 64
#define NEG_ (-1.0e30f)

typedef short bf16x8 __attribute__((ext_vector_type(8)));
typedef float f32x4 __attribute__((ext_vector_type(4)));

__device__ inline short f2bf(float f) {  // fp32 -> bf16 bits, RNE
  union { float f; unsigned u; } v; v.f = f;
  unsigned r = v.u + 0x7FFF + ((v.u >> 16) & 1);
  return (short)(r >> 16);
}

// ---------------------------------------------------------------------------
// fp32 -> bf16 convert (grid-stride-free, exact-size launches)
// ---------------------------------------------------------------------------
__global__ __launch_bounds__(256) void cvt_bf16(const float* __restrict__ src,
                                                short* __restrict__ dst, int n4) {
  int i = blockIdx.x * 256 + threadIdx.x;
  if (i < n4) {
    float4 f = ((const float4*)src)[i];
    short4 o;
    o.x = f2bf(f.x); o.y = f2bf(f.y); o.z = f2bf(f.z); o.w = f2bf(f.w);
    ((short4*)dst)[i] = o;
  }
}

// ---------------------------------------------------------------------------
// MFMA GEMM 128x128 tile, BK=32, 4 waves (2x2), each wave 64x64 = 4x4 MFMA tiles.
// Layouts (HW-verified): A-frag A[m=l15][k=quad*8+j]; B-frag B[k=quad*8+j][n=l15];
// C/D: row=quad*4+reg, col=l15.
// gemm_qkv: Y = Xb @ Winb^T; epilogue fuses RoPE (first 32 dims of q,k) and
// scatters bf16 to q/k/v [b*8+h][s][d].
// ---------------------------------------------------------------------------
__global__ __launch_bounds__(256) void gemm_qkv_mfma(
    const short* __restrict__ Xb,    // [8192][512] bf16
    const short* __restrict__ Wb,    // [1536][512] bf16
    short* __restrict__ qb, short* __restrict__ kb, short* __restrict__ vb) {
  __shared__ __align__(16) short As[128][40];
  __shared__ __align__(16) short Bs[128][40];
  const int tid = threadIdx.x;
  const int w = tid >> 6, lane = tid & 63;
  const int l15 = lane & 15, quad = lane >> 4;
  const int wm = w & 1, wn = w >> 1;
  const int m0 = blockIdx.x * 128;
  const int n0 = blockIdx.y * 128;
  f32x4 acc[4][4];
  for (int mt = 0; mt < 4; ++mt)
    for (int nt = 0; nt < 4; ++nt) acc[mt][nt] = (f32x4){0.f, 0.f, 0.f, 0.f};

  for (int k0 = 0; k0 < E_; k0 += 32) {
    __syncthreads();
    for (int l = 0; l < 2; ++l) {
      int c = tid + 256 * l;               // 512 chunks of 8 shorts
      int row = c >> 2, k8 = (c & 3) * 8;
      *(bf16x8*)&As[row][k8] = *(const bf16x8*)&Xb[(size_t)(m0 + row) * E_ + k0 + k8];
      *(bf16x8*)&Bs[row][k8] = *(const bf16x8*)&Wb[(size_t)(n0 + row) * E_ + k0 + k8];
    }
    __syncthreads();
    bf16x8 a[4], bfr[4];
    for (int mt = 0; mt < 4; ++mt)
      a[mt] = *(const bf16x8*)&As[wm * 64 + mt * 16 + l15][quad * 8];
    for (int nt = 0; nt < 4; ++nt)
      bfr[nt] = *(const bf16x8*)&Bs[wn * 64 + nt * 16 + l15][quad * 8];
    for (int mt = 0; mt < 4; ++mt)
      for (int nt = 0; nt < 4; ++nt)
        acc[mt][nt] = __builtin_amdgcn_mfma_f32_16x16x32_bf16(a[mt], bfr[nt], acc[mt][nt], 0, 0, 0);
  }
  // epilogue: fused RoPE + scatter
  const int t3 = n0 >> 9;                  // uniform per block: 0=q 1=k 2=v
  short* dst = (t3 == 0) ? qb : ((t3 == 1) ? kb : vb);
  for (int nt = 0; nt < 4; ++nt) {
    const int n = n0 + wn * 64 + nt * 16 + l15;
    const int h = (n >> 6) & 7;
    const int d = n & 63;
    const bool dorope = (t3 < 2) && (d < 32);   // uniform per nt
    const float sgn = (d & 1) ? 1.f : -1.f;
    const float fr = dorope ? powf(10000.f, -(float)(2 * (d >> 1)) * (1.f / 32.f)) : 0.f;
    for (int mt = 0; mt < 4; ++mt) {
      for (int i = 0; i < 4; ++i) {
        const int m = m0 + wm * 64 + mt * 16 + quad * 4 + i;
        const int b = m >> 11, s = m & (S_ - 1);
        float val = acc[mt][nt][i];
        float pv = __shfl_xor(val, 1, 64);   // paired rope element (col ^ 1)
        float outv = val;
        if (dorope) {
          float ang = (float)s * fr;
          float sn, cs;
          sincosf(ang, &sn, &cs);
          outv = val * cs + pv * sgn * sn;
        }
        dst[(((size_t)(b * 8 + h)) * S_ + s) * D_ + d] = f2bf(outv);
      }
    }
  }
}

// ---------------------------------------------------------------------------
// gemm_out: out = ob @ Woutb^T, fp32 output
// ---------------------------------------------------------------------------
__global__ __launch_bounds__(256) void gemm_out_mfma(
    const short* __restrict__ Ab,    // [8192][512] bf16 (attn)
    const short* __restrict__ Wb,    // [512][512] bf16
    float* __restrict__ out) {
  __shared__ __align__(16) short As[128][40];
  __shared__ __align__(16) short Bs[128][40];
  const int tid = threadIdx.x;
  const int w = tid >> 6, lane = tid & 63;
  const int l15 = lane & 15, quad = lane >> 4;
  const int wm = w & 1, wn = w >> 1;
  const int m0 = blockIdx.x * 128;
  const int n0 = blockIdx.y * 128;
  f32x4 acc[4][4];
  for (int mt = 0; mt < 4; ++mt)
    for (int nt = 0; nt < 4; ++nt) acc[mt][nt] = (f32x4){0.f, 0.f, 0.f, 0.f};

  for (int k0 = 0; k0 < E_; k0 += 32) {
    __syncthreads();
    for (int l = 0; l < 2; ++l) {
      int c = tid + 256 * l;
      int row = c >> 2, k8 = (c & 3) * 8;
      *(bf16x8*)&As[row][k8] = *(const bf16x8*)&Ab[(size_t)(m0 + row) * E_ + k0 + k8];
      *(bf16x8*)&Bs[row][k8] = *(const bf16x8*)&Wb[(size_t)(n0 + row) * E_ + k0 + k8];
    }
    __syncthreads();
    bf16x8 a[4], bfr[4];
    for (int mt = 0; mt < 4; ++mt)
      a[mt] = *(const bf16x8*)&As[wm * 64 + mt * 16 + l15][quad * 8];
    for (int nt = 0; nt < 4; ++nt)
      bfr[nt] = *(const bf16x8*)&Bs[wn * 64 + nt * 16 + l15][quad * 8];
    for (int mt = 0; mt < 4; ++mt)
      for (int nt = 0; nt < 4; ++nt)
        acc[mt][nt] = __builtin_amdgcn_mfma_f32_16x16x32_bf16(a[mt], bfr[nt], acc[mt][nt], 0, 0, 0);
  }
  for (int mt = 0; mt < 4; ++mt)
    for (int nt = 0; nt < 4; ++nt) {
      const int n = n0 + wn * 64 + nt * 16 + l15;
      for (int i = 0; i < 4; ++i) {
        const int m = m0 + wm * 64 + mt * 16 + quad * 4 + i;
        out[(size_t)m * E_ + n] = acc[mt][nt][i];
      }
    }
}

// ---------------------------------------------------------------------------
// Flash attention via MFMA, bf16 inputs/outputs. Structure as round 4 (passed),
// with conversion-free staging and direct bf16 Q-frag loads.
// ---------------------------------------------------------------------------
__global__ __launch_bounds__(256) void flash_mfma(
    const short* __restrict__ qb, const short* __restrict__ kb,
    const short* __restrict__ vb, const int* __restrict__ maskp,
    short* __restrict__ ob) {
  __shared__ short Ks[32][72];
  __shared__ __align__(16) short VB[4][16][40];
  __shared__ __align__(16) short Pl[4][16][40];
  __shared__ int qmask[64];
  __shared__ int kmask[32];
  const int tid = threadIdx.x;
  const int w = tid >> 6, lane = tid & 63;
  const int l15 = lane & 15, quad = lane >> 4;
  const int bh = blockIdx.y, b = bh >> 3, h = bh & 7;
  const int r0 = blockIdx.x * 64;
  const short* qbase = qb + (size_t)bh * S_ * D_;
  const short* kbase = kb + (size_t)bh * S_ * D_;
  const short* vbase = vb + (size_t)bh * S_ * D_;

  bf16x8 aq[2];
  {
    const short* qrow = qbase + (size_t)(r0 + 16 * w + l15) * D_;
    aq[0] = *(const bf16x8*)&qrow[quad * 8];
    aq[1] = *(const bf16x8*)&qrow[32 + quad * 8];
  }
  if (tid < 64) qmask[tid] = maskp[b * S_ + r0 + tid];

  f32x4 o[4];
  for (int no = 0; no < 4; ++no) o[no] = (f32x4){0.f, 0.f, 0.f, 0.f};
  float m_run[4], l_run[4];
  for (int i = 0; i < 4; ++i) { m_run[i] = NEG_; l_run[i] = 0.f; }

  const int ntiles = (r0 >> 5) + 2;
  for (int kt = 0; kt < ntiles; ++kt) {
    const int t0 = kt * 32;
    __syncthreads();
    {
      const int c = tid >> 3, c0 = (tid & 7) * 8;
      bf16x8 kv = *(const bf16x8*)(kbase + (size_t)(t0 + c) * D_ + c0);
      bf16x8 vv = *(const bf16x8*)(vbase + (size_t)(t0 + c) * D_ + c0);
      *(short4*)&Ks[c][c0]     = (short4){kv[0], kv[1], kv[2], kv[3]};
      *(short4*)&Ks[c][c0 + 4] = (short4){kv[4], kv[5], kv[6], kv[7]};
      for (int j = 0; j < 8; ++j) {
        int col = c0 + j;
        VB[col >> 4][col & 15][c] = vv[j];
      }
      if (tid < 32) kmask[tid] = maskp[b * S_ + t0 + tid];
    }
    __syncthreads();
    f32x4 sfr[2] = {(f32x4){0.f,0.f,0.f,0.f}, (f32x4){0.f,0.f,0.f,0.f}};
    for (int nb = 0; nb < 2; ++nb)
      for (int s = 0; s < 2; ++s) {
        bf16x8 bk = *(const bf16x8*)&Ks[l15 + 16 * nb][32 * s + quad * 8];
        sfr[nb] = __builtin_amdgcn_mfma_f32_16x16x32_bf16(aq[s], bk, sfr[nb], 0, 0, 0);
      }
    float p[2][4], alpha[4];
    for (int i = 0; i < 4; ++i) {
      const int sg = r0 + 16 * w + quad * 4 + i;
      const int qm = qmask[16 * w + quad * 4 + i];
      float msc[2];
      for (int nb = 0; nb < 2; ++nb) {
        const int tg = t0 + l15 + 16 * nb;
        bool ok = (tg <= sg) && (((qm != 0) && (kmask[l15 + 16 * nb] != 0)) || (tg == sg));
        msc[nb] = ok ? sfr[nb][i] * 0.125f : NEG_;
      }
      float lm = fmaxf(msc[0], msc[1]);
      for (int o2 = 1; o2 < 16; o2 <<= 1) lm = fmaxf(lm, __shfl_xor(lm, o2, 64));
      float m_new = fmaxf(m_run[i], lm);
      alpha[i] = __expf(m_run[i] - m_new);
      float ps = 0.f;
      for (int nb = 0; nb < 2; ++nb) {
        float pe = (msc[nb] > -1.0e29f) ? __expf(msc[nb] - m_new) : 0.f;
        p[nb][i] = pe; ps += pe;
      }
      for (int o2 = 1; o2 < 16; o2 <<= 1) ps += __shfl_xor(ps, o2, 64);
      l_run[i] = alpha[i] * l_run[i] + ps;
      m_run[i] = m_new;
    }
    for (int nb = 0; nb < 2; ++nb)
      for (int i = 0; i < 4; ++i)
        Pl[w][quad * 4 + i][l15 + 16 * nb] = f2bf(p[nb][i]);
    for (int no = 0; no < 4; ++no)
      for (int i = 0; i < 4; ++i) o[no][i] *= alpha[i];
    asm volatile("s_waitcnt lgkmcnt(0)" ::: "memory");
    bf16x8 ap = *(const bf16x8*)&Pl[w][l15][quad * 8];
    for (int no = 0; no < 4; ++no) {
      bf16x8 bv = *(const bf16x8*)&VB[no][l15][quad * 8];
      o[no] = __builtin_amdgcn_mfma_f32_16x16x32_bf16(ap, bv, o[no], 0, 0, 0);
    }
  }
  for (int i = 0; i < 4; ++i) {
    const int s = r0 + 16 * w + quad * 4 + i;
    const float inv = 1.f / l_run[i];
    short* orow = ob + ((size_t)(b * S_ + s)) * E_ + h * D_;
    for (int no = 0; no < 4; ++no)
      orow[l15 + 16 * no] = f2bf(o[no][i] * inv);
  }
}

extern "C" void kernel_launch(void* const* d_in, const int* in_sizes, int n_in,
                              void* d_out, int out_size, void* d_ws, size_t ws_size,
                              hipStream_t stream) {
  const float* x    = (const float*)d_in[0];
  const int*   mask = (const int*)d_in[1];
  const float* Win  = (const float*)d_in[2];
  const float* Wout = (const float*)d_in[3];
  float* out = (float*)d_out;

  short* Xb    = (short*)d_ws;               // 8192*512
  short* Winb  = Xb + 8192 * 512;            // 1536*512
  short* Woutb = Winb + 1536 * 512;          // 512*512
  short* qb    = Woutb + 512 * 512;          // 32*2048*64 each
  short* kb    = qb + 32 * 2048 * 64;
  short* vb    = kb + 32 * 2048 * 64;
  short* ob    = vb + 32 * 2048 * 64;        // 8192*512

  cvt_bf16<<<4096, 256, 0, stream>>>(x, Xb, 8192 * 512 / 4);
  cvt_bf16<<<768, 256, 0, stream>>>(Win, Winb, 1536 * 512 / 4);
  cvt_bf16<<<256, 256, 0, stream>>>(Wout, Woutb, 512 * 512 / 4);
  gemm_qkv_mfma<<<dim3(64, 12), 256, 0, stream>>>(Xb, Winb, qb, kb, vb);
  flash_mfma<<<dim3(S_ / 64, 32), 256, 0, stream>>>(qb, kb, vb, mask, ob);
  gemm_out_mfma<<<dim3(64, 4), 256, 0, stream>>>(ob, Woutb, out);
}

// Round 6
// 333.611 us; speedup vs baseline: 46.9838x; 1.1412x over previous
//
#include <hip/hip_runtime.h>
#include <math.h>

// Problem constants
#define B_ 4
#define S_ 2048
#define E_ 512
#define H_ 8
#define D_ 64
#define NEG_ (-1.0e30f)

typedef short bf16x8 __attribute__((ext_vector_type(8)));
typedef float f32x4 __attribute__((ext_vector_type(4)));

__device__ inline short f2bf(float f) {  // fp32 -> bf16 bits, RNE
  union { float f; unsigned u; } v; v.f = f;
  unsigned r = v.u + 0x7FFF + ((v.u >> 16) & 1);
  return (short)(r >> 16);
}

// ---------------------------------------------------------------------------
// fp32 -> bf16 convert
// ---------------------------------------------------------------------------
__global__ __launch_bounds__(256) void cvt_bf16(const float* __restrict__ src,
                                                short* __restrict__ dst, int n4) {
  int i = blockIdx.x * 256 + threadIdx.x;
  if (i < n4) {
    float4 f = ((const float4*)src)[i];
    short4 o;
    o.x = f2bf(f.x); o.y = f2bf(f.y); o.z = f2bf(f.z); o.w = f2bf(f.w);
    ((short4*)dst)[i] = o;
  }
}

// ---------------------------------------------------------------------------
// MFMA GEMM 128x128 tile, BK=32, 4 waves (2x2), each wave 64x64 = 4x4 MFMA tiles.
// gemm_qkv: Y = Xb @ Winb^T; epilogue fuses RoPE and scatters bf16 q/k/v.
// ---------------------------------------------------------------------------
__global__ __launch_bounds__(256) void gemm_qkv_mfma(
    const short* __restrict__ Xb,    // [8192][512] bf16
    const short* __restrict__ Wb,    // [1536][512] bf16
    short* __restrict__ qb, short* __restrict__ kb, short* __restrict__ vb) {
  __shared__ __align__(16) short As[128][40];
  __shared__ __align__(16) short Bs[128][40];
  const int tid = threadIdx.x;
  const int w = tid >> 6, lane = tid & 63;
  const int l15 = lane & 15, quad = lane >> 4;
  const int wm = w & 1, wn = w >> 1;
  const int m0 = blockIdx.x * 128;
  const int n0 = blockIdx.y * 128;
  f32x4 acc[4][4];
  for (int mt = 0; mt < 4; ++mt)
    for (int nt = 0; nt < 4; ++nt) acc[mt][nt] = (f32x4){0.f, 0.f, 0.f, 0.f};

  for (int k0 = 0; k0 < E_; k0 += 32) {
    __syncthreads();
    for (int l = 0; l < 2; ++l) {
      int c = tid + 256 * l;               // 512 chunks of 8 shorts
      int row = c >> 2, k8 = (c & 3) * 8;
      *(bf16x8*)&As[row][k8] = *(const bf16x8*)&Xb[(size_t)(m0 + row) * E_ + k0 + k8];
      *(bf16x8*)&Bs[row][k8] = *(const bf16x8*)&Wb[(size_t)(n0 + row) * E_ + k0 + k8];
    }
    __syncthreads();
    bf16x8 a[4], bfr[4];
    for (int mt = 0; mt < 4; ++mt)
      a[mt] = *(const bf16x8*)&As[wm * 64 + mt * 16 + l15][quad * 8];
    for (int nt = 0; nt < 4; ++nt)
      bfr[nt] = *(const bf16x8*)&Bs[wn * 64 + nt * 16 + l15][quad * 8];
    for (int mt = 0; mt < 4; ++mt)
      for (int nt = 0; nt < 4; ++nt)
        acc[mt][nt] = __builtin_amdgcn_mfma_f32_16x16x32_bf16(a[mt], bfr[nt], acc[mt][nt], 0, 0, 0);
  }
  const int t3 = n0 >> 9;                  // uniform per block: 0=q 1=k 2=v
  short* dst = (t3 == 0) ? qb : ((t3 == 1) ? kb : vb);
  for (int nt = 0; nt < 4; ++nt) {
    const int n = n0 + wn * 64 + nt * 16 + l15;
    const int h = (n >> 6) & 7;
    const int d = n & 63;
    const bool dorope = (t3 < 2) && (d < 32);
    const float sgn = (d & 1) ? 1.f : -1.f;
    const float fr = dorope ? powf(10000.f, -(float)(2 * (d >> 1)) * (1.f / 32.f)) : 0.f;
    for (int mt = 0; mt < 4; ++mt) {
      for (int i = 0; i < 4; ++i) {
        const int m = m0 + wm * 64 + mt * 16 + quad * 4 + i;
        const int b = m >> 11, s = m & (S_ - 1);
        float val = acc[mt][nt][i];
        float pv = __shfl_xor(val, 1, 64);
        float outv = val;
        if (dorope) {
          float ang = (float)s * fr;
          float sn, cs;
          sincosf(ang, &sn, &cs);
          outv = val * cs + pv * sgn * sn;
        }
        dst[(((size_t)(b * 8 + h)) * S_ + s) * D_ + d] = f2bf(outv);
      }
    }
  }
}

// ---------------------------------------------------------------------------
// gemm_out: out = ob @ Woutb^T, fp32 output
// ---------------------------------------------------------------------------
__global__ __launch_bounds__(256) void gemm_out_mfma(
    const short* __restrict__ Ab, const short* __restrict__ Wb,
    float* __restrict__ out) {
  __shared__ __align__(16) short As[128][40];
  __shared__ __align__(16) short Bs[128][40];
  const int tid = threadIdx.x;
  const int w = tid >> 6, lane = tid & 63;
  const int l15 = lane & 15, quad = lane >> 4;
  const int wm = w & 1, wn = w >> 1;
  const int m0 = blockIdx.x * 128;
  const int n0 = blockIdx.y * 128;
  f32x4 acc[4][4];
  for (int mt = 0; mt < 4; ++mt)
    for (int nt = 0; nt < 4; ++nt) acc[mt][nt] = (f32x4){0.f, 0.f, 0.f, 0.f};

  for (int k0 = 0; k0 < E_; k0 += 32) {
    __syncthreads();
    for (int l = 0; l < 2; ++l) {
      int c = tid + 256 * l;
      int row = c >> 2, k8 = (c & 3) * 8;
      *(bf16x8*)&As[row][k8] = *(const bf16x8*)&Ab[(size_t)(m0 + row) * E_ + k0 + k8];
      *(bf16x8*)&Bs[row][k8] = *(const bf16x8*)&Wb[(size_t)(n0 + row) * E_ + k0 + k8];
    }
    __syncthreads();
    bf16x8 a[4], bfr[4];
    for (int mt = 0; mt < 4; ++mt)
      a[mt] = *(const bf16x8*)&As[wm * 64 + mt * 16 + l15][quad * 8];
    for (int nt = 0; nt < 4; ++nt)
      bfr[nt] = *(const bf16x8*)&Bs[wn * 64 + nt * 16 + l15][quad * 8];
    for (int mt = 0; mt < 4; ++mt)
      for (int nt = 0; nt < 4; ++nt)
        acc[mt][nt] = __builtin_amdgcn_mfma_f32_16x16x32_bf16(a[mt], bfr[nt], acc[mt][nt], 0, 0, 0);
  }
  for (int mt = 0; mt < 4; ++mt)
    for (int nt = 0; nt < 4; ++nt) {
      const int n = n0 + wn * 64 + nt * 16 + l15;
      for (int i = 0; i < 4; ++i) {
        const int m = m0 + wm * 64 + mt * 16 + quad * 4 + i;
        out[(size_t)m * E_ + n] = acc[mt][nt][i];
      }
    }
}

// ---------------------------------------------------------------------------
// Flash attention via MFMA, bf16. Causal load balancing: block p processes
// q-tiles r0 = 64p and 1984 - 64p -> every block does the same ~66 inner
// tiles (was 2..66, with same-r0 blocks landing on the same CU: 2x critical
// path). Grid (16, 32).
// ---------------------------------------------------------------------------
__global__ __launch_bounds__(256) void flash_mfma(
    const short* __restrict__ qb, const short* __restrict__ kb,
    const short* __restrict__ vb, const int* __restrict__ maskp,
    short* __restrict__ ob) {
  __shared__ short Ks[32][72];
  __shared__ __align__(16) short VB[4][16][40];
  __shared__ __align__(16) short Pl[4][16][40];
  __shared__ int qmask[64];
  __shared__ int kmask[32];
  const int tid = threadIdx.x;
  const int w = tid >> 6, lane = tid & 63;
  const int l15 = lane & 15, quad = lane >> 4;
  const int bh = blockIdx.y, b = bh >> 3, h = bh & 7;
  const short* qbase = qb + (size_t)bh * S_ * D_;
  const short* kbase = kb + (size_t)bh * S_ * D_;
  const short* vbase = vb + (size_t)bh * S_ * D_;

  for (int seg = 0; seg < 2; ++seg) {
    const int r0 = (seg == 0) ? blockIdx.x * 64 : (S_ - 64) - blockIdx.x * 64;
    __syncthreads();   // prior segment's qmask readers done before overwrite
    if (tid < 64) qmask[tid] = maskp[b * S_ + r0 + tid];

    bf16x8 aq[2];
    {
      const short* qrow = qbase + (size_t)(r0 + 16 * w + l15) * D_;
      aq[0] = *(const bf16x8*)&qrow[quad * 8];
      aq[1] = *(const bf16x8*)&qrow[32 + quad * 8];
    }
    f32x4 o[4];
    for (int no = 0; no < 4; ++no) o[no] = (f32x4){0.f, 0.f, 0.f, 0.f};
    float m_run[4], l_run[4];
    for (int i = 0; i < 4; ++i) { m_run[i] = NEG_; l_run[i] = 0.f; }

    const int ntiles = (r0 >> 5) + 2;
    for (int kt = 0; kt < ntiles; ++kt) {
      const int t0 = kt * 32;
      __syncthreads();   // previous tile (or prior segment's last) consumed
      {
        const int c = tid >> 3, c0 = (tid & 7) * 8;
        bf16x8 kv = *(const bf16x8*)(kbase + (size_t)(t0 + c) * D_ + c0);
        bf16x8 vv = *(const bf16x8*)(vbase + (size_t)(t0 + c) * D_ + c0);
        *(short4*)&Ks[c][c0]     = (short4){kv[0], kv[1], kv[2], kv[3]};
        *(short4*)&Ks[c][c0 + 4] = (short4){kv[4], kv[5], kv[6], kv[7]};
        for (int j = 0; j < 8; ++j) {
          int col = c0 + j;
          VB[col >> 4][col & 15][c] = vv[j];
        }
        if (tid < 32) kmask[tid] = maskp[b * S_ + t0 + tid];
      }
      __syncthreads();
      f32x4 sfr[2] = {(f32x4){0.f,0.f,0.f,0.f}, (f32x4){0.f,0.f,0.f,0.f}};
      for (int nb = 0; nb < 2; ++nb)
        for (int s = 0; s < 2; ++s) {
          bf16x8 bk = *(const bf16x8*)&Ks[l15 + 16 * nb][32 * s + quad * 8];
          sfr[nb] = __builtin_amdgcn_mfma_f32_16x16x32_bf16(aq[s], bk, sfr[nb], 0, 0, 0);
        }
      float p[2][4], alpha[4];
      for (int i = 0; i < 4; ++i) {
        const int sg = r0 + 16 * w + quad * 4 + i;
        const int qm = qmask[16 * w + quad * 4 + i];
        float msc[2];
        for (int nb = 0; nb < 2; ++nb) {
          const int tg = t0 + l15 + 16 * nb;
          bool ok = (tg <= sg) && (((qm != 0) && (kmask[l15 + 16 * nb] != 0)) || (tg == sg));
          msc[nb] = ok ? sfr[nb][i] * 0.125f : NEG_;
        }
        float lm = fmaxf(msc[0], msc[1]);
        for (int o2 = 1; o2 < 16; o2 <<= 1) lm = fmaxf(lm, __shfl_xor(lm, o2, 64));
        float m_new = fmaxf(m_run[i], lm);
        alpha[i] = __expf(m_run[i] - m_new);
        float ps = 0.f;
        for (int nb = 0; nb < 2; ++nb) {
          float pe = (msc[nb] > -1.0e29f) ? __expf(msc[nb] - m_new) : 0.f;
          p[nb][i] = pe; ps += pe;
        }
        for (int o2 = 1; o2 < 16; o2 <<= 1) ps += __shfl_xor(ps, o2, 64);
        l_run[i] = alpha[i] * l_run[i] + ps;
        m_run[i] = m_new;
      }
      for (int nb = 0; nb < 2; ++nb)
        for (int i = 0; i < 4; ++i)
          Pl[w][quad * 4 + i][l15 + 16 * nb] = f2bf(p[nb][i]);
      for (int no = 0; no < 4; ++no)
        for (int i = 0; i < 4; ++i) o[no][i] *= alpha[i];
      asm volatile("s_waitcnt lgkmcnt(0)" ::: "memory");
      bf16x8 ap = *(const bf16x8*)&Pl[w][l15][quad * 8];
      for (int no = 0; no < 4; ++no) {
        bf16x8 bv = *(const bf16x8*)&VB[no][l15][quad * 8];
        o[no] = __builtin_amdgcn_mfma_f32_16x16x32_bf16(ap, bv, o[no], 0, 0, 0);
      }
    }
    for (int i = 0; i < 4; ++i) {
      const int s = r0 + 16 * w + quad * 4 + i;
      const float inv = 1.f / l_run[i];
      short* orow = ob + ((size_t)(b * S_ + s)) * E_ + h * D_;
      for (int no = 0; no < 4; ++no)
        orow[l15 + 16 * no] = f2bf(o[no][i] * inv);
    }
  }
}

extern "C" void kernel_launch(void* const* d_in, const int* in_sizes, int n_in,
                              void* d_out, int out_size, void* d_ws, size_t ws_size,
                              hipStream_t stream) {
  const float* x    = (const float*)d_in[0];
  const int*   mask = (const int*)d_in[1];
  const float* Win  = (const float*)d_in[2];
  const float* Wout = (const float*)d_in[3];
  float* out = (float*)d_out;

  short* Xb    = (short*)d_ws;               // 8192*512
  short* Winb  = Xb + 8192 * 512;            // 1536*512
  short* Woutb = Winb + 1536 * 512;          // 512*512
  short* qb    = Woutb + 512 * 512;          // 32*2048*64 each
  short* kb    = qb + 32 * 2048 * 64;
  short* vb    = kb + 32 * 2048 * 64;
  short* ob    = vb + 32 * 2048 * 64;        // 8192*512

  cvt_bf16<<<4096, 256, 0, stream>>>(x, Xb, 8192 * 512 / 4);
  cvt_bf16<<<768, 256, 0, stream>>>(Win, Winb, 1536 * 512 / 4);
  cvt_bf16<<<256, 256, 0, stream>>>(Wout, Woutb, 512 * 512 / 4);
  gemm_qkv_mfma<<<dim3(64, 12), 256, 0, stream>>>(Xb, Winb, qb, kb, vb);
  flash_mfma<<<dim3(16, 32), 256, 0, stream>>>(qb, kb, vb, mask, ob);
  gemm_out_mfma<<<dim3(64, 4), 256, 0, stream>>>(ob, Woutb, out);
}

// Round 7
// 197.994 us; speedup vs baseline: 79.1654x; 1.6850x over previous
//
#include <hip/hip_runtime.h>
#include <math.h>

// Problem constants
#define B_ 4
#define S_ 2048
#define E_ 512
#define H_ 8
#define D_ 64

typedef short bf16x8 __attribute__((ext_vector_type(8)));
typedef float f32x4 __attribute__((ext_vector_type(4)));

__device__ inline short f2bf(float f) {  // fp32 -> bf16 bits, RNE
  union { float f; unsigned u; } v; v.f = f;
  unsigned r = v.u + 0x7FFF + ((v.u >> 16) & 1);
  return (short)(r >> 16);
}

// ---------------------------------------------------------------------------
// fp32 -> bf16 convert
// ---------------------------------------------------------------------------
__global__ __launch_bounds__(256) void cvt_bf16(const float* __restrict__ src,
                                                short* __restrict__ dst, int n4) {
  int i = blockIdx.x * 256 + threadIdx.x;
  if (i < n4) {
    float4 f = ((const float4*)src)[i];
    short4 o;
    o.x = f2bf(f.x); o.y = f2bf(f.y); o.z = f2bf(f.z); o.w = f2bf(f.w);
    ((short4*)dst)[i] = o;
  }
}

// ---------------------------------------------------------------------------
// MFMA GEMM 128x128 tile, BK=32, 4 waves (2x2). gemm_qkv: Y = Xb @ Winb^T;
// epilogue fuses RoPE; q,k stored [bh][s][d]; V stored TRANSPOSED [bh][d][s]
// so flash can stage it conflict-free with vector copies.
// ---------------------------------------------------------------------------
__global__ __launch_bounds__(256) void gemm_qkv_mfma(
    const short* __restrict__ Xb,    // [8192][512] bf16
    const short* __restrict__ Wb,    // [1536][512] bf16
    short* __restrict__ qb, short* __restrict__ kb, short* __restrict__ vbT) {
  __shared__ __align__(16) short As[128][40];
  __shared__ __align__(16) short Bs[128][40];
  const int tid = threadIdx.x;
  const int w = tid >> 6, lane = tid & 63;
  const int l15 = lane & 15, quad = lane >> 4;
  const int wm = w & 1, wn = w >> 1;
  const int m0 = blockIdx.x * 128;
  const int n0 = blockIdx.y * 128;
  f32x4 acc[4][4];
  for (int mt = 0; mt < 4; ++mt)
    for (int nt = 0; nt < 4; ++nt) acc[mt][nt] = (f32x4){0.f, 0.f, 0.f, 0.f};

  for (int k0 = 0; k0 < E_; k0 += 32) {
    __syncthreads();
    for (int l = 0; l < 2; ++l) {
      int c = tid + 256 * l;
      int row = c >> 2, k8 = (c & 3) * 8;
      *(bf16x8*)&As[row][k8] = *(const bf16x8*)&Xb[(size_t)(m0 + row) * E_ + k0 + k8];
      *(bf16x8*)&Bs[row][k8] = *(const bf16x8*)&Wb[(size_t)(n0 + row) * E_ + k0 + k8];
    }
    __syncthreads();
    bf16x8 a[4], bfr[4];
    for (int mt = 0; mt < 4; ++mt)
      a[mt] = *(const bf16x8*)&As[wm * 64 + mt * 16 + l15][quad * 8];
    for (int nt = 0; nt < 4; ++nt)
      bfr[nt] = *(const bf16x8*)&Bs[wn * 64 + nt * 16 + l15][quad * 8];
    for (int mt = 0; mt < 4; ++mt)
      for (int nt = 0; nt < 4; ++nt)
        acc[mt][nt] = __builtin_amdgcn_mfma_f32_16x16x32_bf16(a[mt], bfr[nt], acc[mt][nt], 0, 0, 0);
  }
  const int t3 = n0 >> 9;                  // uniform per block: 0=q 1=k 2=v
  for (int nt = 0; nt < 4; ++nt) {
    const int n = n0 + wn * 64 + nt * 16 + l15;
    const int h = (n >> 6) & 7;
    const int d = n & 63;
    const bool dorope = (t3 < 2) && (d < 32);
    const float sgn = (d & 1) ? 1.f : -1.f;
    const float fr = dorope ? powf(10000.f, -(float)(2 * (d >> 1)) * (1.f / 32.f)) : 0.f;
    for (int mt = 0; mt < 4; ++mt) {
      for (int i = 0; i < 4; ++i) {
        const int m = m0 + wm * 64 + mt * 16 + quad * 4 + i;
        const int b = m >> 11, s = m & (S_ - 1);
        float val = acc[mt][nt][i];
        float pv = __shfl_xor(val, 1, 64);
        float outv = val;
        if (dorope) {
          float ang = (float)s * fr;
          float sn, cs;
          sincosf(ang, &sn, &cs);
          outv = val * cs + pv * sgn * sn;
        }
        if (t3 == 2)
          vbT[((size_t)(b * 8 + h) * D_ + d) * S_ + s] = f2bf(outv);
        else {
          short* dst = (t3 == 0) ? qb : kb;
          dst[(((size_t)(b * 8 + h)) * S_ + s) * D_ + d] = f2bf(outv);
        }
      }
    }
  }
}

// ---------------------------------------------------------------------------
// gemm_out: out = ob @ Woutb^T, fp32 output
// ---------------------------------------------------------------------------
__global__ __launch_bounds__(256) void gemm_out_mfma(
    const short* __restrict__ Ab, const short* __restrict__ Wb,
    float* __restrict__ out) {
  __shared__ __align__(16) short As[128][40];
  __shared__ __align__(16) short Bs[128][40];
  const int tid = threadIdx.x;
  const int w = tid >> 6, lane = tid & 63;
  const int l15 = lane & 15, quad = lane >> 4;
  const int wm = w & 1, wn = w >> 1;
  const int m0 = blockIdx.x * 128;
  const int n0 = blockIdx.y * 128;
  f32x4 acc[4][4];
  for (int mt = 0; mt < 4; ++mt)
    for (int nt = 0; nt < 4; ++nt) acc[mt][nt] = (f32x4){0.f, 0.f, 0.f, 0.f};

  for (int k0 = 0; k0 < E_; k0 += 32) {
    __syncthreads();
    for (int l = 0; l < 2; ++l) {
      int c = tid + 256 * l;
      int row = c >> 2, k8 = (c & 3) * 8;
      *(bf16x8*)&As[row][k8] = *(const bf16x8*)&Ab[(size_t)(m0 + row) * E_ + k0 + k8];
      *(bf16x8*)&Bs[row][k8] = *(const bf16x8*)&Wb[(size_t)(n0 + row) * E_ + k0 + k8];
    }
    __syncthreads();
    bf16x8 a[4], bfr[4];
    for (int mt = 0; mt < 4; ++mt)
      a[mt] = *(const bf16x8*)&As[wm * 64 + mt * 16 + l15][quad * 8];
    for (int nt = 0; nt < 4; ++nt)
      bfr[nt] = *(const bf16x8*)&Bs[wn * 64 + nt * 16 + l15][quad * 8];
    for (int mt = 0; mt < 4; ++mt)
      for (int nt = 0; nt < 4; ++nt)
        acc[mt][nt] = __builtin_amdgcn_mfma_f32_16x16x32_bf16(a[mt], bfr[nt], acc[mt][nt], 0, 0, 0);
  }
  for (int mt = 0; mt < 4; ++mt)
    for (int nt = 0; nt < 4; ++nt) {
      const int n = n0 + wn * 64 + nt * 16 + l15;
      for (int i = 0; i < 4; ++i) {
        const int m = m0 + wm * 64 + mt * 16 + quad * 4 + i;
        out[(size_t)m * E_ + n] = acc[mt][nt][i];
      }
    }
}

// ---------------------------------------------------------------------------
// Flash attention, MFMA, static-max softmax (exact after normalization).
// BR=64 (16 rows/wave), BC=64. Block p does q-tiles 64p and 1984-64p (33
// inner tiles each -> balanced). Row-masked (mask[s]=0) rows = V[s], applied
// in epilogue; inner loop only needs column mask + causal on the single
// boundary tile (t0 == r0). Row sums via all-ones-B MFMA (no shuffles).
// ---------------------------------------------------------------------------
__global__ __launch_bounds__(256) void flash_mfma(
    const short* __restrict__ qb, const short* __restrict__ kb,
    const short* __restrict__ vbT, const int* __restrict__ maskp,
    short* __restrict__ ob) {
  __shared__ __align__(16) short Ks[64][72];
  __shared__ __align__(16) short VT[64][72];
  __shared__ __align__(16) short Pl[4][16][72];
  __shared__ float kmf[64];
  const int tid = threadIdx.x;
  const int w = tid >> 6, lane = tid & 63;
  const int l15 = lane & 15, quad = lane >> 4;
  const int bh = blockIdx.y, b = bh >> 3, h = bh & 7;
  const short* qbase = qb + (size_t)bh * S_ * D_;
  const short* kbase = kb + (size_t)bh * S_ * D_;
  const short* vtb   = vbT + (size_t)bh * D_ * S_;
  bf16x8 ones;
  for (int j = 0; j < 8; ++j) ones[j] = (short)0x3F80;  // bf16 1.0

  for (int seg = 0; seg < 2; ++seg) {
    const int r0 = (seg == 0) ? blockIdx.x * 64 : (S_ - 64) - blockIdx.x * 64;
    bf16x8 aq[2];
    {
      const short* qrow = qbase + (size_t)(r0 + 16 * w + l15) * D_;
      aq[0] = *(const bf16x8*)&qrow[quad * 8];
      aq[1] = *(const bf16x8*)&qrow[32 + quad * 8];
    }
    f32x4 o[4], lsum;
    for (int no = 0; no < 4; ++no) o[no] = (f32x4){0.f, 0.f, 0.f, 0.f};
    lsum = (f32x4){0.f, 0.f, 0.f, 0.f};

    const int lastkt = r0 >> 6;
    for (int kt = 0; kt <= lastkt; ++kt) {
      const int t0 = kt * 64;
      __syncthreads();               // prior tile fully consumed by all waves
      for (int l = 0; l < 2; ++l) {
        int idx = tid + 256 * l;
        int row = idx >> 3, ch = (idx & 7) * 8;
        *(bf16x8*)&Ks[row][ch] = *(const bf16x8*)(kbase + (size_t)(t0 + row) * D_ + ch);
        *(bf16x8*)&VT[row][ch] = *(const bf16x8*)(vtb + (size_t)row * S_ + t0 + ch);
      }
      if (tid < 64) kmf[tid] = maskp[b * S_ + t0 + tid] ? 1.f : 0.f;
      __syncthreads();
      // S = Q K^T : 4 col-blocks x 2 k-slices
      f32x4 sfr[4];
      for (int nb = 0; nb < 4; ++nb) sfr[nb] = (f32x4){0.f, 0.f, 0.f, 0.f};
      for (int nb = 0; nb < 4; ++nb)
        for (int ks = 0; ks < 2; ++ks) {
          bf16x8 bk = *(const bf16x8*)&Ks[l15 + 16 * nb][32 * ks + quad * 8];
          sfr[nb] = __builtin_amdgcn_mfma_f32_16x16x32_bf16(aq[ks], bk, sfr[nb], 0, 0, 0);
        }
      // p = exp(s/8 - 16) * colmask  (static max: exact after normalization)
      const bool boundary = (kt == lastkt);
      for (int nb = 0; nb < 4; ++nb) {
        const float km = kmf[l15 + 16 * nb];
        const int tg = l15 + 16 * nb;
        for (int i = 0; i < 4; ++i) {
          float pm = km;
          if (boundary && tg > 16 * w + quad * 4 + i) pm = 0.f;
          float p = __expf(sfr[nb][i] * 0.125f - 16.f) * pm;
          Pl[w][quad * 4 + i][l15 + 16 * nb] = f2bf(p);
        }
      }
      asm volatile("s_waitcnt lgkmcnt(0)" ::: "memory");  // own-wave Pl writes
      bf16x8 ap0 = *(const bf16x8*)&Pl[w][l15][quad * 8];
      bf16x8 ap1 = *(const bf16x8*)&Pl[w][l15][32 + quad * 8];
      for (int no = 0; no < 4; ++no) {
        bf16x8 bv0 = *(const bf16x8*)&VT[16 * no + l15][quad * 8];
        bf16x8 bv1 = *(const bf16x8*)&VT[16 * no + l15][32 + quad * 8];
        o[no] = __builtin_amdgcn_mfma_f32_16x16x32_bf16(ap0, bv0, o[no], 0, 0, 0);
        o[no] = __builtin_amdgcn_mfma_f32_16x16x32_bf16(ap1, bv1, o[no], 0, 0, 0);
      }
      lsum = __builtin_amdgcn_mfma_f32_16x16x32_bf16(ap0, ones, lsum, 0, 0, 0);
      lsum = __builtin_amdgcn_mfma_f32_16x16x32_bf16(ap1, ones, lsum, 0, 0, 0);
    }
    // epilogue: rows with mask=0 output V[s] exactly; else normalize
    for (int i = 0; i < 4; ++i) {
      const int s = r0 + 16 * w + quad * 4 + i;
      const int qm = maskp[b * S_ + s];
      const float inv = 1.f / lsum[i];
      short* orow = ob + ((size_t)(b * S_ + s)) * E_ + h * D_;
      for (int no = 0; no < 4; ++no) {
        const int d = l15 + 16 * no;
        orow[d] = qm ? f2bf(o[no][i] * inv) : vtb[(size_t)d * S_ + s];
      }
    }
  }
}

extern "C" void kernel_launch(void* const* d_in, const int* in_sizes, int n_in,
                              void* d_out, int out_size, void* d_ws, size_t ws_size,
                              hipStream_t stream) {
  const float* x    = (const float*)d_in[0];
  const int*   mask = (const int*)d_in[1];
  const float* Win  = (const float*)d_in[2];
  const float* Wout = (const float*)d_in[3];
  float* out = (float*)d_out;

  short* Xb    = (short*)d_ws;               // 8192*512
  short* Winb  = Xb + 8192 * 512;            // 1536*512
  short* Woutb = Winb + 1536 * 512;          // 512*512
  short* qb    = Woutb + 512 * 512;          // 32*2048*64 each
  short* kb    = qb + 32 * 2048 * 64;
  short* vbT   = kb + 32 * 2048 * 64;        // [bh][d][s] transposed
  short* ob    = vbT + 32 * 2048 * 64;       // 8192*512

  cvt_bf16<<<4096, 256, 0, stream>>>(x, Xb, 8192 * 512 / 4);
  cvt_bf16<<<768, 256, 0, stream>>>(Win, Winb, 1536 * 512 / 4);
  cvt_bf16<<<256, 256, 0, stream>>>(Wout, Woutb, 512 * 512 / 4);
  gemm_qkv_mfma<<<dim3(64, 12), 256, 0, stream>>>(Xb, Winb, qb, kb, vbT);
  flash_mfma<<<dim3(16, 32), 256, 0, stream>>>(qb, kb, vbT, mask, ob);
  gemm_out_mfma<<<dim3(64, 4), 256, 0, stream>>>(ob, Woutb, out);
}